// Round 17
// baseline (107.637 us; speedup 1.0000x reference)
//
#include <hip/hip_runtime.h>
#include <hip/hip_bf16.h>

#define N_IN 128
#define N_OUT 64
#define BSHIFT 6                 // 64 nodes per bucket
#define BNODES 64
#define MAXB 2048                // supports nN up to 131072
#define CAP 2048                 // slot capacity per bucket (mean 1024, +32 sigma)
#define SUB 256                  // per-XCD-group sub-slot (mean 128, +11 sigma)

typedef short bf16x8 __attribute__((ext_vector_type(8)));
typedef float f32x4 __attribute__((ext_vector_type(4)));

__device__ inline short f2bf(float x) {
    __hip_bfloat16 b = __float2bfloat16(x);
    union { __hip_bfloat16 b; short s; } u;
    u.b = b;
    return u.s;
}

__device__ inline float bflo(unsigned int v) { return __uint_as_float(v << 16); }
__device__ inline float bfhi(unsigned int v) { return __uint_as_float(v & 0xffff0000u); }

// ---- init per-(xcdgroup,bucket) cursors to sub-slot bases ----
__global__ __launch_bounds__(1024) void initcur_kernel(int* __restrict__ cursorS,
                                                       int* __restrict__ cursorD) {
    for (int i = threadIdx.x; i < 8 * MAXB; i += 1024) {
        int x = i >> 11;              // xcd group (MAXB=2048)
        int b = i & (MAXB - 1);       // bucket
        int v = b * CAP + x * SUB;
        cursorS[i] = v;
        cursorD[i] = v;
    }
}

// ---- fused bucket-sorts, XCD-partitioned sub-slots; bufS as u8 (low 6 bits needed) ----
__global__ __launch_bounds__(512) void fillSB_kernel(const int* __restrict__ src,
                                                     const int* __restrict__ dst,
                                                     int* __restrict__ cursorS,
                                                     int* __restrict__ cursorD,
                                                     unsigned char* __restrict__ bufS,
                                                     unsigned int* __restrict__ bufD,
                                                     int nE, int nB) {
    __shared__ int hS[MAXB];
    __shared__ int hD[MAXB];
    __shared__ int lbS[MAXB];
    __shared__ int lbD[MAXB];
    int t = threadIdx.x;
    for (int i = t; i < nB; i += 512) { hS[i] = 0; hD[i] = 0; }
    __syncthreads();

    int xg = blockIdx.x & 7;                   // XCD group (round-robin dispatch)
    int* curS = cursorS + xg * MAXB;
    int* curD = cursorD + xg * MAXB;

    int e0 = blockIdx.x * 2048 + t;
    int sv[4], dv[4];
#pragma unroll
    for (int j = 0; j < 4; ++j) {
        int e = e0 + j * 512;
        if (e < nE) {
            sv[j] = src[e];
            dv[j] = dst[e];
            atomicAdd(&hS[sv[j] >> BSHIFT], 1);
            atomicAdd(&hD[dv[j] >> BSHIFT], 1);
        } else {
            sv[j] = -1;
            dv[j] = 0;
        }
    }
    __syncthreads();
    for (int i = t; i < nB; i += 512) {
        int c = hS[i];
        lbS[i] = c ? atomicAdd(&curS[i], c) : 0;
        c = hD[i];
        lbD[i] = c ? atomicAdd(&curD[i], c) : 0;
    }
    __syncthreads();
#pragma unroll
    for (int j = 0; j < 4; ++j) {
        if (sv[j] >= 0) {
            int ps = atomicAdd(&lbS[sv[j] >> BSHIFT], 1);
            bufS[ps] = (unsigned char)(sv[j] & (BNODES - 1));
            int pd = atomicAdd(&lbD[dv[j] >> BSHIFT], 1);
            bufD[pd] = ((unsigned int)sv[j] << BSHIFT) | (unsigned int)(dv[j] & (BNODES - 1));
        }
    }
}

// ---- per src-bucket: count the 64 node slots over 8 sub-segments; write nrm directly ----
__global__ __launch_bounds__(256) void countS_kernel(const unsigned char* __restrict__ bufS,
                                                     const int* __restrict__ cursorS,
                                                     float* __restrict__ nrm, int nN) {
    __shared__ int hist[BNODES];
    int t = threadIdx.x;
    if (t < BNODES) hist[t] = 0;
    __syncthreads();
    int b = blockIdx.x;
#pragma unroll
    for (int x = 0; x < 8; ++x) {
        int s0 = b * CAP + x * SUB;
        int len = cursorS[x * MAXB + b] - s0;
        for (int i = t; i < len; i += 256)
            atomicAdd(&hist[bufS[s0 + i] & (BNODES - 1)], 1);
    }
    __syncthreads();
    int node = b * BNODES + t;
    if (t < BNODES && node < nN)
        nrm[node] = rsqrtf(fmaxf((float)hist[t], 1.0f));
}

// ---- h = bf16( (feat @ W) * norm[:,None] ) via MFMA; A staged through LDS (coalesced) ----
__global__ __launch_bounds__(256) void gemm_kernel(const float* __restrict__ feat,
                                                   const float* __restrict__ w,
                                                   const float* __restrict__ nrm,
                                                   __hip_bfloat16* __restrict__ h, int nN) {
    __shared__ short wt[N_OUT][N_IN + 8];    // W^T bf16, pad 8 (17.4 KB)
    __shared__ short fa[64][N_IN + 8];       // A tile bf16, pad 8 (17.4 KB)
    int t = threadIdx.x;
    for (int i = t; i < N_IN * N_OUT; i += 256) {
        int k = i >> 6, c = i & 63;
        wt[c][k] = f2bf(w[i]);
    }
    int tileBase = blockIdx.x * 64;
    for (int f = t; f < 64 * (N_IN / 4); f += 256) {
        int r = f >> 5;                       // row 0..63
        int cq = f & 31;                      // col-quad
        int node = min(tileBase + r, nN - 1);
        float4 v = *(const float4*)&feat[(size_t)node * N_IN + cq * 4];
        short4 s4;
        s4.x = f2bf(v.x); s4.y = f2bf(v.y); s4.z = f2bf(v.z); s4.w = f2bf(v.w);
        *(short4*)&fa[r][cq * 4] = s4;
    }
    __syncthreads();

    int wv = t >> 6, l = t & 63;
    int c16 = l & 15;
    int kq  = l >> 4;
    int rloc = wv * 16 + c16;
    int waveBase = tileBase + wv * 16;

    f32x4 acc[4];
#pragma unroll
    for (int ct = 0; ct < 4; ++ct) acc[ct] = (f32x4){0.f, 0.f, 0.f, 0.f};

#pragma unroll
    for (int ks = 0; ks < 4; ++ks) {
        bf16x8 av = *(const bf16x8*)&fa[rloc][ks * 32 + kq * 8];
#pragma unroll
        for (int ct = 0; ct < 4; ++ct) {
            bf16x8 bf = *(const bf16x8*)&wt[ct * 16 + c16][ks * 32 + kq * 8];
            acc[ct] = __builtin_amdgcn_mfma_f32_16x16x32_bf16(av, bf, acc[ct], 0, 0, 0);
        }
    }

    // D layout (m89-verified): col = lane&15, row = 4*(lane>>4) + reg
#pragma unroll
    for (int r = 0; r < 4; ++r) {
        int node = waveBase + 4 * kq + r;
        if (node < nN) {
            float nn = nrm[node];
#pragma unroll
            for (int ct = 0; ct < 4; ++ct) {
                short v = f2bf(acc[ct][r] * nn);
                *(short*)&h[(size_t)node * N_OUT + ct * 16 + c16] = v;
            }
        }
    }
}

// ---- aggregate: stage->LDS, two-array counting-sort, group-per-row ILP-4 walk ----
__global__ __launch_bounds__(512) void agg_kernel(const unsigned int* __restrict__ bufD,
                                                  const int* __restrict__ cursorD,
                                                  const __hip_bfloat16* __restrict__ h,
                                                  const float* __restrict__ nrm,
                                                  const float* __restrict__ bias,
                                                  float* __restrict__ out, int nN) {
    __shared__ unsigned int stage[CAP];      // 8 KB
    __shared__ unsigned int sorted_[CAP];    // 8 KB
    __shared__ int hist[BNODES];
    __shared__ int ssh[BNODES];
    __shared__ int sbase[BNODES];
    __shared__ int scur[BNODES];
    int t = threadIdx.x;
    int lane = t & 63, wv = t >> 6;          // 8 waves; wave owns rows wv*8..+7
    int g = lane >> 4;                       // group 0..3 (16 lanes each)
    int li = lane & 15;                      // lane-in-group; cols li*4..+3

    int b = blockIdx.x;

    // phase A: gather the bucket's 8 sub-segments contiguously into stage
    int off = 0;
#pragma unroll
    for (int x = 0; x < 8; ++x) {
        int s0 = b * CAP + x * SUB;
        int len = cursorD[x * MAXB + b] - s0;
        for (int i = t; i < len; i += 512) stage[off + i] = bufD[s0 + i];
        off += len;
    }
    int cnt = off;                           // <= CAP

    for (int i = t; i < BNODES; i += 512) hist[i] = 0;
    __syncthreads();                         // stage visible; hist zeroed

    unsigned int pk[CAP / 512];
#pragma unroll
    for (int j = 0; j < CAP / 512; ++j) {
        int e = t + j * 512;
        if (e < cnt) {
            pk[j] = stage[e];
            atomicAdd(&hist[pk[j] & (BNODES - 1)], 1);
        } else {
            pk[j] = 0xFFFFFFFFu;
        }
    }
    __syncthreads();

    // exclusive scan of hist[64]
    if (t < BNODES) ssh[t] = hist[t];
    __syncthreads();
    for (int o = 1; o < BNODES; o <<= 1) {
        int x = 0;
        if (t < BNODES && t >= o) x = ssh[t - o];
        __syncthreads();
        if (t < BNODES) ssh[t] += x;
        __syncthreads();
    }
    if (t < BNODES) {
        int ex = (t == 0) ? 0 : ssh[t - 1];
        sbase[t] = ex;
        scur[t] = ex;
    }
    __syncthreads();

    // scatter into sorted_ (two-array; stage never overwritten)
#pragma unroll
    for (int j = 0; j < CAP / 512; ++j) {
        if (pk[j] != 0xFFFFFFFFu) {
            int pos = atomicAdd(&scur[pk[j] & (BNODES - 1)], 1);
            sorted_[pos] = pk[j];
        }
    }
    __syncthreads();                         // scur[r] now == row end

    float4 acc[2];                           // acc[r]: row wv*8 + r*4 + g
#pragma unroll
    for (int r = 0; r < 2; ++r) acc[r] = (float4){0.f, 0.f, 0.f, 0.f};

    // group-per-row walk: group g owns row wv*8 + r*4 + g; stride-1 ILP-4, uint2 gathers
#pragma unroll
    for (int r = 0; r < 2; ++r) {
        int row = wv * 8 + r * 4 + g;
        int e = sbase[row], ee = scur[row];
        float4 a = acc[r];
        for (; e + 3 < ee; e += 4) {
            unsigned int p0 = sorted_[e];
            unsigned int p1 = sorted_[e + 1];
            unsigned int p2 = sorted_[e + 2];
            unsigned int p3 = sorted_[e + 3];
            uint2 v0 = *(const uint2*)&h[(size_t)(p0 >> BSHIFT) * N_OUT + li * 4];
            uint2 v1 = *(const uint2*)&h[(size_t)(p1 >> BSHIFT) * N_OUT + li * 4];
            uint2 v2 = *(const uint2*)&h[(size_t)(p2 >> BSHIFT) * N_OUT + li * 4];
            uint2 v3 = *(const uint2*)&h[(size_t)(p3 >> BSHIFT) * N_OUT + li * 4];
            a.x += bflo(v0.x); a.y += bfhi(v0.x); a.z += bflo(v0.y); a.w += bfhi(v0.y);
            a.x += bflo(v1.x); a.y += bfhi(v1.x); a.z += bflo(v1.y); a.w += bfhi(v1.y);
            a.x += bflo(v2.x); a.y += bfhi(v2.x); a.z += bflo(v2.y); a.w += bfhi(v2.y);
            a.x += bflo(v3.x); a.y += bfhi(v3.x); a.z += bflo(v3.y); a.w += bfhi(v3.y);
        }
        for (; e < ee; ++e) {
            unsigned int p = sorted_[e];
            uint2 v = *(const uint2*)&h[(size_t)(p >> BSHIFT) * N_OUT + li * 4];
            a.x += bflo(v.x); a.y += bfhi(v.x); a.z += bflo(v.y); a.w += bfhi(v.y);
        }
        acc[r] = a;
    }

    // epilogue: each group writes its 2 rows; float4 per lane (coalesced 256B/row)
    float4 bl = ((const float4*)bias)[li];
    int nodeB = b * BNODES + wv * 8;
#pragma unroll
    for (int r = 0; r < 2; ++r) {
        int node = nodeB + r * 4 + g;
        if (node < nN) {
            float nn = nrm[node];
            float4 o4;
            o4.x = acc[r].x * nn + bl.x;
            o4.y = acc[r].y * nn + bl.y;
            o4.z = acc[r].z * nn + bl.z;
            o4.w = acc[r].w * nn + bl.w;
            *(float4*)&out[(size_t)node * N_OUT + li * 4] = o4;
        }
    }
}

extern "C" void kernel_launch(void* const* d_in, const int* in_sizes, int n_in,
                              void* d_out, int out_size, void* d_ws, size_t ws_size,
                              hipStream_t stream) {
    const float* feat = (const float*)d_in[0];
    const float* w    = (const float*)d_in[1];
    const float* bias = (const float*)d_in[2];
    const int*   src  = (const int*)d_in[3];
    const int*   dst  = (const int*)d_in[4];
    float* out = (float*)d_out;

    int nN = in_sizes[0] / N_IN;      // 100000
    int nE = in_sizes[3];             // 1600000
    int nB = (nN + BNODES - 1) >> BSHIFT;   // 1563

    // ---- workspace layout (~30 MB; ws_size = 256 MiB) ----
    size_t o = 0;
    auto alloc = [&](size_t bytes) { size_t r = o; o = (o + bytes + 1023) & ~(size_t)1023; return r; };
    char* wsc = (char*)d_ws;
    float* nrm    = (float*)(wsc + alloc((size_t)nN * 4));
    int* cursorS  = (int*)(wsc + alloc((size_t)(8 * MAXB) * 4));
    int* cursorD  = (int*)(wsc + alloc((size_t)(8 * MAXB) * 4));
    unsigned int* bufD  = (unsigned int*)(wsc + alloc((size_t)nB * CAP * 4));
    unsigned char* bufS = (unsigned char*)(wsc + alloc((size_t)nB * CAP));
    __hip_bfloat16* h   = (__hip_bfloat16*)(wsc + alloc((size_t)nN * N_OUT * 2));

    int nblk = (nE + 2047) / 2048;    // 782
    initcur_kernel<<<1, 1024, 0, stream>>>(cursorS, cursorD);
    fillSB_kernel<<<nblk, 512, 0, stream>>>(src, dst, cursorS, cursorD, bufS, bufD, nE, nB);
    countS_kernel<<<nB, 256, 0, stream>>>(bufS, cursorS, nrm, nN);
    gemm_kernel<<<(nN + 63) / 64, 256, 0, stream>>>(feat, w, nrm, h, nN);
    agg_kernel<<<nB, 512, 0, stream>>>(bufD, cursorD, h, nrm, bias, out, nN);
}

// Round 18
// 98.359 us; speedup vs baseline: 1.0943x; 1.0943x over previous
//
#include <hip/hip_runtime.h>
#include <hip/hip_bf16.h>

#define N_IN 128
#define N_OUT 64
#define BSHIFT 7                 // 128 nodes per bucket
#define BNODES 128
#define MAXB 1024                // supports nN up to 131072
#define CAP 4096                 // slot capacity per bucket (mean 2046)
#define SUB 512                  // per-XCD-group sub-slot (mean 256, +16 sigma)

typedef short bf16x8 __attribute__((ext_vector_type(8)));
typedef float f32x4 __attribute__((ext_vector_type(4)));

__device__ inline short f2bf(float x) {
    __hip_bfloat16 b = __float2bfloat16(x);
    union { __hip_bfloat16 b; short s; } u;
    u.b = b;
    return u.s;
}

__device__ inline float bflo(unsigned int v) { return __uint_as_float(v << 16); }
__device__ inline float bfhi(unsigned int v) { return __uint_as_float(v & 0xffff0000u); }

// ---- init per-(xcdgroup,bucket) cursors to sub-slot bases ----
__global__ __launch_bounds__(1024) void initcur_kernel(int* __restrict__ cursorS,
                                                       int* __restrict__ cursorD) {
    for (int i = threadIdx.x; i < 8 * MAXB; i += 1024) {
        int x = i >> 10;              // xcd group
        int b = i & (MAXB - 1);       // bucket
        int v = b * CAP + x * SUB;
        cursorS[i] = v;
        cursorD[i] = v;
    }
}

// ---- fused bucket-sorts, XCD-partitioned sub-slots; bufS as u8 (only low 7 bits needed) ----
__global__ __launch_bounds__(512) void fillSB_kernel(const int* __restrict__ src,
                                                     const int* __restrict__ dst,
                                                     int* __restrict__ cursorS,
                                                     int* __restrict__ cursorD,
                                                     unsigned char* __restrict__ bufS,
                                                     unsigned int* __restrict__ bufD,
                                                     int nE, int nB) {
    __shared__ int hS[MAXB];
    __shared__ int hD[MAXB];
    __shared__ int lbS[MAXB];
    __shared__ int lbD[MAXB];
    int t = threadIdx.x;
    for (int i = t; i < nB; i += 512) { hS[i] = 0; hD[i] = 0; }
    __syncthreads();

    int xg = blockIdx.x & 7;                   // XCD group (round-robin dispatch)
    int* curS = cursorS + xg * MAXB;
    int* curD = cursorD + xg * MAXB;

    int e0 = blockIdx.x * 2048 + t;
    int sv[4], dv[4];
#pragma unroll
    for (int j = 0; j < 4; ++j) {
        int e = e0 + j * 512;
        if (e < nE) {
            sv[j] = src[e];
            dv[j] = dst[e];
            atomicAdd(&hS[sv[j] >> BSHIFT], 1);
            atomicAdd(&hD[dv[j] >> BSHIFT], 1);
        } else {
            sv[j] = -1;
            dv[j] = 0;
        }
    }
    __syncthreads();
    for (int i = t; i < nB; i += 512) {
        int c = hS[i];
        lbS[i] = c ? atomicAdd(&curS[i], c) : 0;
        c = hD[i];
        lbD[i] = c ? atomicAdd(&curD[i], c) : 0;
    }
    __syncthreads();
#pragma unroll
    for (int j = 0; j < 4; ++j) {
        if (sv[j] >= 0) {
            int ps = atomicAdd(&lbS[sv[j] >> BSHIFT], 1);
            bufS[ps] = (unsigned char)(sv[j] & (BNODES - 1));
            int pd = atomicAdd(&lbD[dv[j] >> BSHIFT], 1);
            bufD[pd] = ((unsigned int)sv[j] << BSHIFT) | (unsigned int)(dv[j] & (BNODES - 1));
        }
    }
}

// ---- per src-bucket: count the 128 node slots over 8 sub-segments; write nrm directly ----
__global__ __launch_bounds__(256) void countS_kernel(const unsigned char* __restrict__ bufS,
                                                     const int* __restrict__ cursorS,
                                                     float* __restrict__ nrm, int nN) {
    __shared__ int hist[BNODES];
    int t = threadIdx.x;
    if (t < BNODES) hist[t] = 0;
    __syncthreads();
    int b = blockIdx.x;
#pragma unroll
    for (int x = 0; x < 8; ++x) {
        int s0 = b * CAP + x * SUB;
        int len = cursorS[x * MAXB + b] - s0;
        for (int i = t; i < len; i += 256)
            atomicAdd(&hist[bufS[s0 + i] & (BNODES - 1)], 1);
    }
    __syncthreads();
    int node = b * BNODES + t;
    if (t < BNODES && node < nN)
        nrm[node] = rsqrtf(fmaxf((float)hist[t], 1.0f));
}

// ---- h = bf16( (feat @ W) * norm[:,None] ) via MFMA; A staged through LDS (coalesced) ----
__global__ __launch_bounds__(256) void gemm_kernel(const float* __restrict__ feat,
                                                   const float* __restrict__ w,
                                                   const float* __restrict__ nrm,
                                                   __hip_bfloat16* __restrict__ h, int nN) {
    __shared__ short wt[N_OUT][N_IN + 8];    // W^T bf16, pad 8 (17.4 KB)
    __shared__ short fa[64][N_IN + 8];       // A tile bf16, pad 8 (17.4 KB)
    int t = threadIdx.x;
    for (int i = t; i < N_IN * N_OUT; i += 256) {
        int k = i >> 6, c = i & 63;
        wt[c][k] = f2bf(w[i]);
    }
    int tileBase = blockIdx.x * 64;
    for (int f = t; f < 64 * (N_IN / 4); f += 256) {
        int r = f >> 5;                       // row 0..63
        int cq = f & 31;                      // col-quad
        int node = min(tileBase + r, nN - 1);
        float4 v = *(const float4*)&feat[(size_t)node * N_IN + cq * 4];
        short4 s4;
        s4.x = f2bf(v.x); s4.y = f2bf(v.y); s4.z = f2bf(v.z); s4.w = f2bf(v.w);
        *(short4*)&fa[r][cq * 4] = s4;
    }
    __syncthreads();

    int wv = t >> 6, l = t & 63;
    int c16 = l & 15;
    int kq  = l >> 4;
    int rloc = wv * 16 + c16;
    int waveBase = tileBase + wv * 16;

    f32x4 acc[4];
#pragma unroll
    for (int ct = 0; ct < 4; ++ct) acc[ct] = (f32x4){0.f, 0.f, 0.f, 0.f};

#pragma unroll
    for (int ks = 0; ks < 4; ++ks) {
        bf16x8 av = *(const bf16x8*)&fa[rloc][ks * 32 + kq * 8];
#pragma unroll
        for (int ct = 0; ct < 4; ++ct) {
            bf16x8 bf = *(const bf16x8*)&wt[ct * 16 + c16][ks * 32 + kq * 8];
            acc[ct] = __builtin_amdgcn_mfma_f32_16x16x32_bf16(av, bf, acc[ct], 0, 0, 0);
        }
    }

    // D layout (m89-verified): col = lane&15, row = 4*(lane>>4) + reg
#pragma unroll
    for (int r = 0; r < 4; ++r) {
        int node = waveBase + 4 * kq + r;
        if (node < nN) {
            float nn = nrm[node];
#pragma unroll
            for (int ct = 0; ct < 4; ++ct) {
                short v = f2bf(acc[ct][r] * nn);
                *(short*)&h[(size_t)node * N_OUT + ct * 16 + c16] = v;
            }
        }
    }
}

// ---- aggregate: 2 blocks per bucket (64 rows each); stage full bucket, filter, sort, walk ----
__global__ __launch_bounds__(512) void agg_kernel(const unsigned int* __restrict__ bufD,
                                                  const int* __restrict__ cursorD,
                                                  const __hip_bfloat16* __restrict__ h,
                                                  const float* __restrict__ nrm,
                                                  const float* __restrict__ bias,
                                                  float* __restrict__ out, int nN) {
    __shared__ unsigned int stage[CAP];      // 16 KB
    __shared__ unsigned int sorted_[CAP];    // 16 KB (worst case: all edges in one half)
    __shared__ int hist[64];
    __shared__ int ssh[64];
    __shared__ int sbase[64];
    __shared__ int scur[64];
    int t = threadIdx.x;
    int lane = t & 63, wv = t >> 6;          // 8 waves; wave owns local rows wv*8..+7
    int g = lane >> 4;                       // group 0..3 (16 lanes each)
    int li = lane & 15;                      // lane-in-group; cols li*4..+3

    int b = blockIdx.x >> 1;                 // bucket
    int half = blockIdx.x & 1;               // which 64-row half this block owns

    // phase A: gather the bucket's 8 sub-segments contiguously into stage
    int off = 0;
#pragma unroll
    for (int x = 0; x < 8; ++x) {
        int s0 = b * CAP + x * SUB;
        int len = cursorD[x * MAXB + b] - s0;
        for (int i = t; i < len; i += 512) stage[off + i] = bufD[s0 + i];
        off += len;
    }
    int cnt = off;                           // <= CAP

    if (t < 64) hist[t] = 0;
    __syncthreads();                         // stage visible; hist zeroed

    unsigned int pk[CAP / 512];
#pragma unroll
    for (int j = 0; j < CAP / 512; ++j) {
        int e = t + j * 512;
        unsigned int p = (e < cnt) ? stage[e] : 0xFFFFFFFFu;
        if (p != 0xFFFFFFFFu) {
            int r7 = p & (BNODES - 1);
            if ((r7 >> 6) == half) {
                atomicAdd(&hist[r7 & 63], 1);
            } else {
                p = 0xFFFFFFFFu;             // other half's edge: drop
            }
        }
        pk[j] = p;
    }
    __syncthreads();

    // exclusive scan of hist[64]
    if (t < 64) ssh[t] = hist[t];
    __syncthreads();
    for (int o = 1; o < 64; o <<= 1) {
        int x = 0;
        if (t < 64 && t >= o) x = ssh[t - o];
        __syncthreads();
        if (t < 64) ssh[t] += x;
        __syncthreads();
    }
    if (t < 64) {
        int ex = (t == 0) ? 0 : ssh[t - 1];
        sbase[t] = ex;
        scur[t] = ex;
    }
    __syncthreads();

    // scatter into sorted_ (two-array; stage never overwritten)
#pragma unroll
    for (int j = 0; j < CAP / 512; ++j) {
        if (pk[j] != 0xFFFFFFFFu) {
            int pos = atomicAdd(&scur[pk[j] & 63], 1);
            sorted_[pos] = pk[j];
        }
    }
    __syncthreads();                         // scur[r] now == row end

    float4 acc[2];                           // acc[r]: local row wv*8 + r*4 + g
#pragma unroll
    for (int r = 0; r < 2; ++r) acc[r] = (float4){0.f, 0.f, 0.f, 0.f};

    // group-per-row walk: group g owns local row wv*8 + r*4 + g; stride-1 ILP-4, uint2 gathers
#pragma unroll
    for (int r = 0; r < 2; ++r) {
        int row = wv * 8 + r * 4 + g;
        int e = sbase[row], ee = scur[row];
        float4 a = acc[r];
        for (; e + 3 < ee; e += 4) {
            unsigned int p0 = sorted_[e];
            unsigned int p1 = sorted_[e + 1];
            unsigned int p2 = sorted_[e + 2];
            unsigned int p3 = sorted_[e + 3];
            uint2 v0 = *(const uint2*)&h[(size_t)(p0 >> BSHIFT) * N_OUT + li * 4];
            uint2 v1 = *(const uint2*)&h[(size_t)(p1 >> BSHIFT) * N_OUT + li * 4];
            uint2 v2 = *(const uint2*)&h[(size_t)(p2 >> BSHIFT) * N_OUT + li * 4];
            uint2 v3 = *(const uint2*)&h[(size_t)(p3 >> BSHIFT) * N_OUT + li * 4];
            a.x += bflo(v0.x); a.y += bfhi(v0.x); a.z += bflo(v0.y); a.w += bfhi(v0.y);
            a.x += bflo(v1.x); a.y += bfhi(v1.x); a.z += bflo(v1.y); a.w += bfhi(v1.y);
            a.x += bflo(v2.x); a.y += bfhi(v2.x); a.z += bflo(v2.y); a.w += bfhi(v2.y);
            a.x += bflo(v3.x); a.y += bfhi(v3.x); a.z += bflo(v3.y); a.w += bfhi(v3.y);
        }
        for (; e < ee; ++e) {
            unsigned int p = sorted_[e];
            uint2 v = *(const uint2*)&h[(size_t)(p >> BSHIFT) * N_OUT + li * 4];
            a.x += bflo(v.x); a.y += bfhi(v.x); a.z += bflo(v.y); a.w += bfhi(v.y);
        }
        acc[r] = a;
    }

    // epilogue: each group writes its 2 rows; float4 per lane (coalesced 256B/row)
    float4 bl = ((const float4*)bias)[li];
    int nodeB = b * BNODES + half * 64 + wv * 8;
#pragma unroll
    for (int r = 0; r < 2; ++r) {
        int node = nodeB + r * 4 + g;
        if (node < nN) {
            float nn = nrm[node];
            float4 o4;
            o4.x = acc[r].x * nn + bl.x;
            o4.y = acc[r].y * nn + bl.y;
            o4.z = acc[r].z * nn + bl.z;
            o4.w = acc[r].w * nn + bl.w;
            *(float4*)&out[(size_t)node * N_OUT + li * 4] = o4;
        }
    }
}

extern "C" void kernel_launch(void* const* d_in, const int* in_sizes, int n_in,
                              void* d_out, int out_size, void* d_ws, size_t ws_size,
                              hipStream_t stream) {
    const float* feat = (const float*)d_in[0];
    const float* w    = (const float*)d_in[1];
    const float* bias = (const float*)d_in[2];
    const int*   src  = (const int*)d_in[3];
    const int*   dst  = (const int*)d_in[4];
    float* out = (float*)d_out;

    int nN = in_sizes[0] / N_IN;      // 100000
    int nE = in_sizes[3];             // 1600000
    int nB = (nN + BNODES - 1) >> BSHIFT;   // 782

    // ---- workspace layout (~30 MB; ws_size = 256 MiB) ----
    size_t o = 0;
    auto alloc = [&](size_t bytes) { size_t r = o; o = (o + bytes + 1023) & ~(size_t)1023; return r; };
    char* wsc = (char*)d_ws;
    float* nrm    = (float*)(wsc + alloc((size_t)nN * 4));
    int* cursorS  = (int*)(wsc + alloc((size_t)(8 * MAXB) * 4));
    int* cursorD  = (int*)(wsc + alloc((size_t)(8 * MAXB) * 4));
    unsigned int* bufD  = (unsigned int*)(wsc + alloc((size_t)nB * CAP * 4));
    unsigned char* bufS = (unsigned char*)(wsc + alloc((size_t)nB * CAP));
    __hip_bfloat16* h   = (__hip_bfloat16*)(wsc + alloc((size_t)nN * N_OUT * 2));

    int nblk = (nE + 2047) / 2048;    // 782
    initcur_kernel<<<1, 1024, 0, stream>>>(cursorS, cursorD);
    fillSB_kernel<<<nblk, 512, 0, stream>>>(src, dst, cursorS, cursorD, bufS, bufD, nE, nB);
    countS_kernel<<<nB, 256, 0, stream>>>(bufS, cursorS, nrm, nN);
    gemm_kernel<<<(nN + 63) / 64, 256, 0, stream>>>(feat, w, nrm, h, nN);
    agg_kernel<<<nB * 2, 512, 0, stream>>>(bufD, cursorD, h, nrm, bias, out, nN);
}

// Round 19
// 95.075 us; speedup vs baseline: 1.1321x; 1.0345x over previous
//
#include <hip/hip_runtime.h>
#include <hip/hip_bf16.h>

#define N_IN 128
#define N_OUT 64
#define BSHIFT 7                 // 128 nodes per bucket
#define BNODES 128
#define MAXB 1024                // supports nN up to 131072
#define CAP 4096                 // slot capacity per bucket (mean 2046)
#define SUB 512                  // per-XCD-group sub-slot (mean 256, +16 sigma)

typedef short bf16x8 __attribute__((ext_vector_type(8)));
typedef float f32x4 __attribute__((ext_vector_type(4)));

__device__ inline short f2bf(float x) {
    __hip_bfloat16 b = __float2bfloat16(x);
    union { __hip_bfloat16 b; short s; } u;
    u.b = b;
    return u.s;
}

__device__ inline float bflo(unsigned int v) { return __uint_as_float(v << 16); }
__device__ inline float bfhi(unsigned int v) { return __uint_as_float(v & 0xffff0000u); }

// ---- init per-(xcdgroup,bucket) cursors to sub-slot bases ----
__global__ __launch_bounds__(1024) void initcur_kernel(int* __restrict__ cursorS,
                                                       int* __restrict__ cursorD) {
    for (int i = threadIdx.x; i < 8 * MAXB; i += 1024) {
        int x = i >> 10;              // xcd group
        int b = i & (MAXB - 1);       // bucket
        int v = b * CAP + x * SUB;
        cursorS[i] = v;
        cursorD[i] = v;
    }
}

// ---- fused bucket-sorts, XCD-partitioned sub-slots; bufS as u8 (only low 7 bits needed) ----
__global__ __launch_bounds__(512) void fillSB_kernel(const int* __restrict__ src,
                                                     const int* __restrict__ dst,
                                                     int* __restrict__ cursorS,
                                                     int* __restrict__ cursorD,
                                                     unsigned char* __restrict__ bufS,
                                                     unsigned int* __restrict__ bufD,
                                                     int nE, int nB) {
    __shared__ int hS[MAXB];
    __shared__ int hD[MAXB];
    __shared__ int lbS[MAXB];
    __shared__ int lbD[MAXB];
    int t = threadIdx.x;
    for (int i = t; i < nB; i += 512) { hS[i] = 0; hD[i] = 0; }
    __syncthreads();

    int xg = blockIdx.x & 7;                   // XCD group (round-robin dispatch)
    int* curS = cursorS + xg * MAXB;
    int* curD = cursorD + xg * MAXB;

    int e0 = blockIdx.x * 2048 + t;
    int sv[4], dv[4];
#pragma unroll
    for (int j = 0; j < 4; ++j) {
        int e = e0 + j * 512;
        if (e < nE) {
            sv[j] = src[e];
            dv[j] = dst[e];
            atomicAdd(&hS[sv[j] >> BSHIFT], 1);
            atomicAdd(&hD[dv[j] >> BSHIFT], 1);
        } else {
            sv[j] = -1;
            dv[j] = 0;
        }
    }
    __syncthreads();
    for (int i = t; i < nB; i += 512) {
        int c = hS[i];
        lbS[i] = c ? atomicAdd(&curS[i], c) : 0;
        c = hD[i];
        lbD[i] = c ? atomicAdd(&curD[i], c) : 0;
    }
    __syncthreads();
#pragma unroll
    for (int j = 0; j < 4; ++j) {
        if (sv[j] >= 0) {
            int ps = atomicAdd(&lbS[sv[j] >> BSHIFT], 1);
            bufS[ps] = (unsigned char)(sv[j] & (BNODES - 1));
            int pd = atomicAdd(&lbD[dv[j] >> BSHIFT], 1);
            bufD[pd] = ((unsigned int)sv[j] << BSHIFT) | (unsigned int)(dv[j] & (BNODES - 1));
        }
    }
}

// ---- per src-bucket: count the 128 node slots over 8 sub-segments; write nrm directly ----
__global__ __launch_bounds__(256) void countS_kernel(const unsigned char* __restrict__ bufS,
                                                     const int* __restrict__ cursorS,
                                                     float* __restrict__ nrm, int nN) {
    __shared__ int hist[BNODES];
    int t = threadIdx.x;
    if (t < BNODES) hist[t] = 0;
    __syncthreads();
    int b = blockIdx.x;
#pragma unroll
    for (int x = 0; x < 8; ++x) {
        int s0 = b * CAP + x * SUB;
        int len = cursorS[x * MAXB + b] - s0;
        for (int i = t; i < len; i += 256)
            atomicAdd(&hist[bufS[s0 + i] & (BNODES - 1)], 1);
    }
    __syncthreads();
    int node = b * BNODES + t;
    if (t < BNODES && node < nN)
        nrm[node] = rsqrtf(fmaxf((float)hist[t], 1.0f));
}

// ---- h = bf16( (feat @ W) * norm[:,None] ) via MFMA; A staged through LDS (coalesced) ----
__global__ __launch_bounds__(256) void gemm_kernel(const float* __restrict__ feat,
                                                   const float* __restrict__ w,
                                                   const float* __restrict__ nrm,
                                                   __hip_bfloat16* __restrict__ h, int nN) {
    __shared__ short wt[N_OUT][N_IN + 8];    // W^T bf16, pad 8 (17.4 KB)
    __shared__ short fa[64][N_IN + 8];       // A tile bf16, pad 8 (17.4 KB)
    int t = threadIdx.x;
    for (int i = t; i < N_IN * N_OUT; i += 256) {
        int k = i >> 6, c = i & 63;
        wt[c][k] = f2bf(w[i]);
    }
    int tileBase = blockIdx.x * 64;
    for (int f = t; f < 64 * (N_IN / 4); f += 256) {
        int r = f >> 5;                       // row 0..63
        int cq = f & 31;                      // col-quad
        int node = min(tileBase + r, nN - 1);
        float4 v = *(const float4*)&feat[(size_t)node * N_IN + cq * 4];
        short4 s4;
        s4.x = f2bf(v.x); s4.y = f2bf(v.y); s4.z = f2bf(v.z); s4.w = f2bf(v.w);
        *(short4*)&fa[r][cq * 4] = s4;
    }
    __syncthreads();

    int wv = t >> 6, l = t & 63;
    int c16 = l & 15;
    int kq  = l >> 4;
    int rloc = wv * 16 + c16;
    int waveBase = tileBase + wv * 16;

    f32x4 acc[4];
#pragma unroll
    for (int ct = 0; ct < 4; ++ct) acc[ct] = (f32x4){0.f, 0.f, 0.f, 0.f};

#pragma unroll
    for (int ks = 0; ks < 4; ++ks) {
        bf16x8 av = *(const bf16x8*)&fa[rloc][ks * 32 + kq * 8];
#pragma unroll
        for (int ct = 0; ct < 4; ++ct) {
            bf16x8 bf = *(const bf16x8*)&wt[ct * 16 + c16][ks * 32 + kq * 8];
            acc[ct] = __builtin_amdgcn_mfma_f32_16x16x32_bf16(av, bf, acc[ct], 0, 0, 0);
        }
    }

    // D layout (m89-verified): col = lane&15, row = 4*(lane>>4) + reg
#pragma unroll
    for (int r = 0; r < 4; ++r) {
        int node = waveBase + 4 * kq + r;
        if (node < nN) {
            float nn = nrm[node];
#pragma unroll
            for (int ct = 0; ct < 4; ++ct) {
                short v = f2bf(acc[ct][r] * nn);
                *(short*)&h[(size_t)node * N_OUT + ct * 16 + c16] = v;
            }
        }
    }
}

// ---- aggregate: stage->LDS, two-array counting-sort, 8-lane-group uint4 ILP-4 walk ----
__global__ __launch_bounds__(512) void agg_kernel(const unsigned int* __restrict__ bufD,
                                                  const int* __restrict__ cursorD,
                                                  const __hip_bfloat16* __restrict__ h,
                                                  const float* __restrict__ nrm,
                                                  const float* __restrict__ bias,
                                                  float* __restrict__ out, int nN) {
    __shared__ unsigned int stage[CAP];      // 16 KB
    __shared__ unsigned int sorted_[CAP];    // 16 KB
    __shared__ int hist[BNODES];
    __shared__ int ssh[BNODES];
    __shared__ int sbase[BNODES];
    __shared__ int scur[BNODES];
    int t = threadIdx.x;
    int lane = t & 63, wv = t >> 6;          // 8 waves; wave owns rows wv*16..+15
    int g8 = lane >> 3;                      // group 0..7 (8 lanes each)
    int li = lane & 7;                       // lane-in-group; cols li*8..+7

    int b = blockIdx.x;

    // phase A: gather the bucket's 8 sub-segments contiguously into stage
    int off = 0;
#pragma unroll
    for (int x = 0; x < 8; ++x) {
        int s0 = b * CAP + x * SUB;
        int len = cursorD[x * MAXB + b] - s0;
        for (int i = t; i < len; i += 512) stage[off + i] = bufD[s0 + i];
        off += len;
    }
    int cnt = off;                           // <= CAP

    for (int i = t; i < BNODES; i += 512) hist[i] = 0;
    __syncthreads();                         // stage visible; hist zeroed

    unsigned int pk[CAP / 512];
#pragma unroll
    for (int j = 0; j < CAP / 512; ++j) {
        int e = t + j * 512;
        if (e < cnt) {
            pk[j] = stage[e];
            atomicAdd(&hist[pk[j] & (BNODES - 1)], 1);
        } else {
            pk[j] = 0xFFFFFFFFu;
        }
    }
    __syncthreads();

    // exclusive scan of hist[128]
    if (t < BNODES) ssh[t] = hist[t];
    __syncthreads();
    for (int o = 1; o < BNODES; o <<= 1) {
        int x = 0;
        if (t < BNODES && t >= o) x = ssh[t - o];
        __syncthreads();
        if (t < BNODES) ssh[t] += x;
        __syncthreads();
    }
    if (t < BNODES) {
        int ex = (t == 0) ? 0 : ssh[t - 1];
        sbase[t] = ex;
        scur[t] = ex;
    }
    __syncthreads();

    // scatter into sorted_ (two-array; stage never overwritten)
#pragma unroll
    for (int j = 0; j < CAP / 512; ++j) {
        if (pk[j] != 0xFFFFFFFFu) {
            int pos = atomicAdd(&scur[pk[j] & (BNODES - 1)], 1);
            sorted_[pos] = pk[j];
        }
    }
    __syncthreads();                         // scur[r] now == row end

    float acc[2][8];
#pragma unroll
    for (int r = 0; r < 2; ++r)
#pragma unroll
        for (int i = 0; i < 8; ++i) acc[r][i] = 0.0f;

    // walk: group g8 owns rows wv*16 + r*8 + g8; one uint4 (16B) covers lane's 8 cols;
    // 4 edges in flight per group => 8 groups x 4 x 128B row-coverage per wave
#pragma unroll
    for (int r = 0; r < 2; ++r) {
        int row = wv * 16 + r * 8 + g8;
        int e = sbase[row], ee = scur[row];
        for (; e + 3 < ee; e += 4) {
            unsigned int p0 = sorted_[e];
            unsigned int p1 = sorted_[e + 1];
            unsigned int p2 = sorted_[e + 2];
            unsigned int p3 = sorted_[e + 3];
            uint4 v0 = *(const uint4*)&h[(size_t)(p0 >> BSHIFT) * N_OUT + li * 8];
            uint4 v1 = *(const uint4*)&h[(size_t)(p1 >> BSHIFT) * N_OUT + li * 8];
            uint4 v2 = *(const uint4*)&h[(size_t)(p2 >> BSHIFT) * N_OUT + li * 8];
            uint4 v3 = *(const uint4*)&h[(size_t)(p3 >> BSHIFT) * N_OUT + li * 8];
            acc[r][0] += bflo(v0.x); acc[r][1] += bfhi(v0.x);
            acc[r][2] += bflo(v0.y); acc[r][3] += bfhi(v0.y);
            acc[r][4] += bflo(v0.z); acc[r][5] += bfhi(v0.z);
            acc[r][6] += bflo(v0.w); acc[r][7] += bfhi(v0.w);
            acc[r][0] += bflo(v1.x); acc[r][1] += bfhi(v1.x);
            acc[r][2] += bflo(v1.y); acc[r][3] += bfhi(v1.y);
            acc[r][4] += bflo(v1.z); acc[r][5] += bfhi(v1.z);
            acc[r][6] += bflo(v1.w); acc[r][7] += bfhi(v1.w);
            acc[r][0] += bflo(v2.x); acc[r][1] += bfhi(v2.x);
            acc[r][2] += bflo(v2.y); acc[r][3] += bfhi(v2.y);
            acc[r][4] += bflo(v2.z); acc[r][5] += bfhi(v2.z);
            acc[r][6] += bflo(v2.w); acc[r][7] += bfhi(v2.w);
            acc[r][0] += bflo(v3.x); acc[r][1] += bfhi(v3.x);
            acc[r][2] += bflo(v3.y); acc[r][3] += bfhi(v3.y);
            acc[r][4] += bflo(v3.z); acc[r][5] += bfhi(v3.z);
            acc[r][6] += bflo(v3.w); acc[r][7] += bfhi(v3.w);
        }
        for (; e < ee; ++e) {
            unsigned int p = sorted_[e];
            uint4 v = *(const uint4*)&h[(size_t)(p >> BSHIFT) * N_OUT + li * 8];
            acc[r][0] += bflo(v.x); acc[r][1] += bfhi(v.x);
            acc[r][2] += bflo(v.y); acc[r][3] += bfhi(v.y);
            acc[r][4] += bflo(v.z); acc[r][5] += bfhi(v.z);
            acc[r][6] += bflo(v.w); acc[r][7] += bfhi(v.w);
        }
    }

    // epilogue: group g8 writes its 2 rows; 2x float4 per lane (256B/row coalesced)
    float4 bl0 = ((const float4*)bias)[li * 2];
    float4 bl1 = ((const float4*)bias)[li * 2 + 1];
    int nodeB = b * BNODES + wv * 16;
#pragma unroll
    for (int r = 0; r < 2; ++r) {
        int node = nodeB + r * 8 + g8;
        if (node < nN) {
            float nn = nrm[node];
            float4 o0, o1;
            o0.x = acc[r][0] * nn + bl0.x;
            o0.y = acc[r][1] * nn + bl0.y;
            o0.z = acc[r][2] * nn + bl0.z;
            o0.w = acc[r][3] * nn + bl0.w;
            o1.x = acc[r][4] * nn + bl1.x;
            o1.y = acc[r][5] * nn + bl1.y;
            o1.z = acc[r][6] * nn + bl1.z;
            o1.w = acc[r][7] * nn + bl1.w;
            *(float4*)&out[(size_t)node * N_OUT + li * 8] = o0;
            *(float4*)&out[(size_t)node * N_OUT + li * 8 + 4] = o1;
        }
    }
}

extern "C" void kernel_launch(void* const* d_in, const int* in_sizes, int n_in,
                              void* d_out, int out_size, void* d_ws, size_t ws_size,
                              hipStream_t stream) {
    const float* feat = (const float*)d_in[0];
    const float* w    = (const float*)d_in[1];
    const float* bias = (const float*)d_in[2];
    const int*   src  = (const int*)d_in[3];
    const int*   dst  = (const int*)d_in[4];
    float* out = (float*)d_out;

    int nN = in_sizes[0] / N_IN;      // 100000
    int nE = in_sizes[3];             // 1600000
    int nB = (nN + BNODES - 1) >> BSHIFT;   // 782

    // ---- workspace layout (~30 MB; ws_size = 256 MiB) ----
    size_t o = 0;
    auto alloc = [&](size_t bytes) { size_t r = o; o = (o + bytes + 1023) & ~(size_t)1023; return r; };
    char* wsc = (char*)d_ws;
    float* nrm    = (float*)(wsc + alloc((size_t)nN * 4));
    int* cursorS  = (int*)(wsc + alloc((size_t)(8 * MAXB) * 4));
    int* cursorD  = (int*)(wsc + alloc((size_t)(8 * MAXB) * 4));
    unsigned int* bufD  = (unsigned int*)(wsc + alloc((size_t)nB * CAP * 4));
    unsigned char* bufS = (unsigned char*)(wsc + alloc((size_t)nB * CAP));
    __hip_bfloat16* h   = (__hip_bfloat16*)(wsc + alloc((size_t)nN * N_OUT * 2));

    int nblk = (nE + 2047) / 2048;    // 782
    initcur_kernel<<<1, 1024, 0, stream>>>(cursorS, cursorD);
    fillSB_kernel<<<nblk, 512, 0, stream>>>(src, dst, cursorS, cursorD, bufS, bufD, nE, nB);
    countS_kernel<<<nB, 256, 0, stream>>>(bufS, cursorS, nrm, nN);
    gemm_kernel<<<(nN + 63) / 64, 256, 0, stream>>>(feat, w, nrm, h, nN);
    agg_kernel<<<nB, 512, 0, stream>>>(bufD, cursorD, h, nrm, bias, out, nN);
}